// Round 1
// baseline (889.196 us; speedup 1.0000x reference)
//
#include <hip/hip_runtime.h>

#define NN 16384      // nodes
#define NE 262144     // edges
#define NSPEC 10
#define KC 64
#define MLPH 16

__device__ __forceinline__ float wave_reduce(float v) {
#pragma unroll
    for (int off = 32; off > 0; off >>= 1) v += __shfl_down(v, off, 64);
    return v;
}

// feats[n][m][k]: m==0 -> W_embed[species[n]], else 0.  float4 over NN*9*16
__global__ void k_init_feats(const float* __restrict__ W_embed,
                             const int* __restrict__ species,
                             float4* __restrict__ feats4) {
    int tid = blockIdx.x * 256 + threadIdx.x;   // 0 .. NN*144-1
    int n = tid / 144;
    int rr = tid - n * 144;
    int m = rr >> 4;
    int q = rr & 15;
    float4 v = make_float4(0.f, 0.f, 0.f, 0.f);
    if (m == 0) {
        int sp = species[n];
        v = reinterpret_cast<const float4*>(W_embed + sp * KC)[q];
    }
    feats4[tid] = v;
}

__global__ void k_hist(const int* __restrict__ receivers, int* __restrict__ count) {
    int e = blockIdx.x * 256 + threadIdx.x;
    atomicAdd(&count[receivers[e]], 1);
}

// exclusive scan of count[0..NN-1] -> row_start[0..NN], one block of 1024, 16 each
__global__ void k_scan(const int* __restrict__ count, int* __restrict__ row_start) {
    __shared__ int lds[1024];
    int t = threadIdx.x;
    int base = t * 16;
    int local[16];
    int s = 0;
#pragma unroll
    for (int b = 0; b < 16; ++b) { local[b] = count[base + b]; s += local[b]; }
    lds[t] = s;
    __syncthreads();
    for (int off = 1; off < 1024; off <<= 1) {
        int v = (t >= off) ? lds[t - off] : 0;
        __syncthreads();
        lds[t] += v;
        __syncthreads();
    }
    int run = lds[t] - s;   // exclusive
#pragma unroll
    for (int b = 0; b < 16; ++b) { row_start[base + b] = run; run += local[b]; }
    if (t == 1023) row_start[NN] = run;
}

// per edge: geometry (Y 9, rad 8) written directly into receiver-sorted slot
__global__ void k_geom(const float* __restrict__ pos,
                       const float* __restrict__ shifts,
                       const int* __restrict__ senders,
                       const int* __restrict__ receivers,
                       const int* __restrict__ row_start,
                       int* __restrict__ cursor,
                       float* __restrict__ Ybuf,
                       float* __restrict__ radb,
                       int* __restrict__ ssort) {
    int e = blockIdx.x * 256 + threadIdx.x;
    int s = senders[e], r = receivers[e];
    float dx = pos[r * 3 + 0] - pos[s * 3 + 0] + shifts[e * 3 + 0];
    float dy = pos[r * 3 + 1] - pos[s * 3 + 1] + shifts[e * 3 + 1];
    float dz = pos[r * 3 + 2] - pos[s * 3 + 2] + shifts[e * 3 + 2];
    float rn = sqrtf(dx * dx + dy * dy + dz * dz);
    float den = (rn > 1e-9f) ? rn : 1.0f;
    float x = dx / den, y = dy / den, z = dz / den;
    const float s3  = 1.7320508075688772f;   // sqrt(3)
    const float s15 = 3.8729833462074170f;   // sqrt(15)
    const float s5h = 1.1180339887498949f;   // sqrt(5)/2
    const float s15h = 1.9364916731037085f;  // sqrt(15)/2
    int p = row_start[r] + atomicAdd(&cursor[r], 1);
    float* Yp = Ybuf + p * 9;
    Yp[0] = 1.0f;
    Yp[1] = s3 * x;
    Yp[2] = s3 * y;
    Yp[3] = s3 * z;
    Yp[4] = s15 * x * y;
    Yp[5] = s15 * y * z;
    Yp[6] = s5h * (3.0f * z * z - 1.0f);
    Yp[7] = s15 * x * z;
    Yp[8] = s15h * (x * x - y * y);
    float u = rn * 0.2f;   // r / R_MAX
    float env = 0.0f;
    if (u < 1.0f) {
        float u2 = u * u;
        float u5 = u2 * u2 * u;
        env = 1.0f - 21.0f * u5 + 35.0f * u5 * u - 15.0f * u5 * u2;
    }
    float pre = 0.63245553203367587f * env / den;   // sqrt(2/R_MAX)*env/r_safe
    float* rp = radb + p * 8;
#pragma unroll
    for (int nb = 1; nb <= 8; ++nb)
        rp[nb - 1] = pre * sinf((float)nb * 3.14159265358979323846f * u);
    ssort[p] = s;
}

// compact l=0 slice of feats into hs0 (NN*KC), float4 over NN*16
__global__ void k_hs0(const float4* __restrict__ feats4, float4* __restrict__ hs04) {
    int tid = blockIdx.x * 256 + threadIdx.x;
    int n = tid >> 4, q = tid & 15;
    hs04[tid] = feats4[n * 144 + q];
}

// one wave per node: A[n][m][k] = (1/16) * sum_edges hs[s][k]*Y[m]*R[l(m)][k]
__global__ void __launch_bounds__(256) k_aggregate(
    const float* __restrict__ hs0,
    const float* __restrict__ Ybuf,
    const float* __restrict__ radb,
    const int* __restrict__ ssort,
    const int* __restrict__ row_start,
    const float* __restrict__ Wr_i,    // W_rad + i*3*8*64, [l][b][k]
    float* __restrict__ A) {
    int wid = threadIdx.x >> 6;
    int lane = threadIdx.x & 63;
    int n = blockIdx.x * 4 + wid;
    float Wr[3][8];
#pragma unroll
    for (int l = 0; l < 3; ++l)
#pragma unroll
        for (int b = 0; b < 8; ++b) Wr[l][b] = Wr_i[(l * 8 + b) * 64 + lane];
    float acc[9];
#pragma unroll
    for (int m = 0; m < 9; ++m) acc[m] = 0.f;
    int e0 = row_start[n], e1 = row_start[n + 1];
    for (int e = e0; e < e1; ++e) {
        int s = ssort[e];
        float h = hs0[s * 64 + lane];
        const float* rp = radb + e * 8;
        float R0 = 0.f, R1 = 0.f, R2 = 0.f;
#pragma unroll
        for (int b = 0; b < 8; ++b) {
            float rb = rp[b];
            R0 += rb * Wr[0][b];
            R1 += rb * Wr[1][b];
            R2 += rb * Wr[2][b];
        }
        float t0 = h * R0, t1 = h * R1, t2 = h * R2;
        const float* Yp = Ybuf + e * 9;
        acc[0] += t0 * Yp[0];
        acc[1] += t1 * Yp[1];
        acc[2] += t1 * Yp[2];
        acc[3] += t1 * Yp[3];
        acc[4] += t2 * Yp[4];
        acc[5] += t2 * Yp[5];
        acc[6] += t2 * Yp[6];
        acc[7] += t2 * Yp[7];
        acc[8] += t2 * Yp[8];
    }
    const float inv_avg = 1.0f / 16.0f;
#pragma unroll
    for (int m = 0; m < 9; ++m) A[n * 576 + m * 64 + lane] = acc[m] * inv_avg;
}

// in-place per-row matvec: A[n][m][:] <- A[n][m][:] @ W_mix[l(m)]
__global__ void __launch_bounds__(256) k_mix(float* __restrict__ A,
                                             const float* __restrict__ Wm_i) {
    int wid = threadIdx.x >> 6;
    int lane = threadIdx.x & 63;
    int row = blockIdx.x * 4 + wid;       // 0 .. NN*9-1
    int m = row % 9;
    int l = (m == 0) ? 0 : ((m < 4) ? 1 : 2);
    float v = A[row * 64 + lane];
    const float* W = Wm_i + l * 64 * 64;
    float acc = 0.f;
#pragma unroll
    for (int k = 0; k < 64; ++k)
        acc += __shfl(v, k, 64) * W[k * 64 + lane];
    A[row * 64 + lane] = acc;
}

// one wave per node: B = A*(w1+w2*A0+w3*inv); sc = feats_old @ W_sc[sp];
// feats_new = B + sc (in place); energy written to out.
template <int ITER>
__global__ void __launch_bounds__(256) k_node(
    float* __restrict__ feats,
    const float* __restrict__ A,
    const int* __restrict__ species,
    const float* __restrict__ Wp_i,     // W_prod + i*3*3*64, [jj][l][k]
    const float* __restrict__ Wsc_i,    // W_sc + i*NSPEC*3*64*64
    const float* __restrict__ W_ro0,
    const float* __restrict__ W_m1,
    const float* __restrict__ b_m1,
    const float* __restrict__ W_m2,
    float* __restrict__ out) {
    __shared__ float fbuf[4][576];
    int wid = threadIdx.x >> 6;
    int lane = threadIdx.x & 63;
    int n = blockIdx.x * 4 + wid;

    float a[9];
#pragma unroll
    for (int m = 0; m < 9; ++m) a[m] = A[n * 576 + m * 64 + lane];
    float A0 = a[0];
    float inv = 0.f;
#pragma unroll
    for (int m = 0; m < 9; ++m) inv += a[m] * a[m];

    float w1[3], w2[3], w3[3];
#pragma unroll
    for (int l = 0; l < 3; ++l) {
        w1[l] = Wp_i[(0 * 3 + l) * 64 + lane];
        w2[l] = Wp_i[(1 * 3 + l) * 64 + lane];
        w3[l] = Wp_i[(2 * 3 + l) * 64 + lane];
    }
    float B[9];
#pragma unroll
    for (int m = 0; m < 9; ++m) {
        int l = (m == 0) ? 0 : ((m < 4) ? 1 : 2);
        B[m] = a[m] * (w1[l] + w2[l] * A0 + w3[l] * inv);
    }

    // stage old feats of this node in LDS
#pragma unroll
    for (int m = 0; m < 9; ++m)
        fbuf[wid][m * 64 + lane] = feats[n * 576 + m * 64 + lane];
    __syncthreads();

    int sp = species[n];
    const float* Wsp = Wsc_i + sp * 3 * 64 * 64;
    float f0new = 0.f;
#pragma unroll
    for (int m = 0; m < 9; ++m) {
        int l = (m == 0) ? 0 : ((m < 4) ? 1 : 2);
        const float* W = Wsp + l * 64 * 64;
        float acc = B[m];
        for (int k = 0; k < 64; ++k)
            acc += fbuf[wid][m * 64 + k] * W[k * 64 + lane];
        feats[n * 576 + m * 64 + lane] = acc;
        if (m == 0) f0new = acc;
    }

    if (ITER == 0) {
        float e = wave_reduce(f0new * W_ro0[lane]);
        if (lane == 0) out[2 * n + 0] = e;
    } else {
        __syncthreads();
        fbuf[wid][lane] = f0new;
        __syncthreads();
        float contrib = 0.f;
        if (lane < MLPH) {
            float t = b_m1[lane];
            for (int k = 0; k < 64; ++k) t += fbuf[wid][k] * W_m1[k * MLPH + lane];
            float sig = 1.0f / (1.0f + expf(-t));
            contrib = t * sig * W_m2[lane];
        }
        float e = wave_reduce(contrib);
        if (lane == 0) out[2 * n + 1] = e;
    }
}

extern "C" void kernel_launch(void* const* d_in, const int* in_sizes, int n_in,
                              void* d_out, int out_size, void* d_ws, size_t ws_size,
                              hipStream_t stream) {
    const float* positions = (const float*)d_in[0];
    const float* shifts    = (const float*)d_in[1];
    const int*   species   = (const int*)d_in[2];
    const int*   senders   = (const int*)d_in[3];
    const int*   receivers = (const int*)d_in[4];
    const float* W_embed   = (const float*)d_in[5];
    const float* W_rad     = (const float*)d_in[6];
    const float* W_mix     = (const float*)d_in[7];
    const float* W_prod    = (const float*)d_in[8];
    const float* W_sc      = (const float*)d_in[9];
    const float* W_ro0     = (const float*)d_in[10];
    const float* W_m1      = (const float*)d_in[11];
    const float* b_m1      = (const float*)d_in[12];
    const float* W_m2      = (const float*)d_in[13];
    float* out = (float*)d_out;

    char* p = (char*)d_ws;
    float* feats = (float*)p; p += (size_t)NN * 576 * 4;   // 37.75 MB
    float* A     = (float*)p; p += (size_t)NN * 576 * 4;   // 37.75 MB
    float* Ybuf  = (float*)p; p += (size_t)NE * 9 * 4;     //  9.44 MB
    float* radb  = (float*)p; p += (size_t)NE * 8 * 4;     //  8.39 MB
    float* hs0   = (float*)p; p += (size_t)NN * KC * 4;    //  4.19 MB
    int* ssort     = (int*)p; p += (size_t)NE * 4;         //  1.05 MB
    int* count     = (int*)p; p += (size_t)NN * 4;
    int* cursor    = (int*)p; p += (size_t)NN * 4;
    int* row_start = (int*)p; p += (size_t)(NN + 1) * 4;

    // zero count+cursor (contiguous)
    hipMemsetAsync(count, 0, (size_t)2 * NN * 4, stream);

    k_init_feats<<<NN * 144 / 256, 256, 0, stream>>>(W_embed, species, (float4*)feats);
    k_hist<<<NE / 256, 256, 0, stream>>>(receivers, count);
    k_scan<<<1, 1024, 0, stream>>>(count, row_start);
    k_geom<<<NE / 256, 256, 0, stream>>>(positions, shifts, senders, receivers,
                                         row_start, cursor, Ybuf, radb, ssort);

    for (int i = 0; i < 2; ++i) {
        k_hs0<<<NN * 16 / 256, 256, 0, stream>>>((const float4*)feats, (float4*)hs0);
        k_aggregate<<<NN / 4, 256, 0, stream>>>(hs0, Ybuf, radb, ssort, row_start,
                                                W_rad + (size_t)i * 3 * 8 * 64, A);
        k_mix<<<NN * 9 / 4, 256, 0, stream>>>(A, W_mix + (size_t)i * 3 * 64 * 64);
        if (i == 0)
            k_node<0><<<NN / 4, 256, 0, stream>>>(feats, A, species,
                W_prod + 0, W_sc + 0, W_ro0, W_m1, b_m1, W_m2, out);
        else
            k_node<1><<<NN / 4, 256, 0, stream>>>(feats, A, species,
                W_prod + 3 * 3 * 64, W_sc + (size_t)NSPEC * 3 * 64 * 64,
                W_ro0, W_m1, b_m1, W_m2, out);
    }
}